// Round 18
// baseline (57.680 us; speedup 1.0000x reference)
//
#include <hip/hip_runtime.h>
#include <hip/hip_fp16.h>
#include <stdint.h>

#define NB    1024
#define IL    4096
#define NOUT  4096
#define FI    128
#define BTILE 8
#define OSPLIT 8
#define OTILE (NOUT / OSPLIT)        // 512 outputs per block
#define SLAB_DW (IL * (BTILE / 2))   // 16384 dwords = 64KB per batch-group slab
#define SLAB_BLOCKS ((NB / BTILE) * IL / 256)   // 2048
#define SORT_BLOCKS (NOUT / 4)                  // 1024 (wave per row)

typedef _Float16 h2v __attribute__((ext_vector_type(2)));
typedef uint32_t u32x4 __attribute__((ext_vector_type(4)));
__device__ __forceinline__ h2v as_h2(uint32_t u){ union{uint32_t u; h2v h;} c; c.u=u; return c.h; }
#if __has_builtin(__builtin_amdgcn_fdot2)
__device__ __forceinline__ float fdot2(h2v a, h2v b, float c){ return __builtin_amdgcn_fdot2(a,b,c,false); }
#else
__device__ __forceinline__ float fdot2(h2v a, h2v b, float c){ return c + (float)a[0]*(float)b[0] + (float)a[1]*(float)b[1]; }
#endif

__device__ __forceinline__ uint32_t f16bits(float x) {
  return (uint32_t)__half_as_ushort(__float2half(x));   // RNE f32->f16
}

// ---------------- merged pre-pass (one launch, unchanged) ----------------
__global__ __launch_bounds__(256)
void prep_kernel(const float* __restrict__ in, uint32_t* __restrict__ slab,
                 const int* __restrict__ idx, const float* __restrict__ w,
                 uint2* __restrict__ pack2) {
  __shared__ uint32_t sbuf[4][FI];
  const int bid = blockIdx.x;
  if (bid < SLAB_BLOCKS) {
    int t = bid * 256 + threadIdx.x;
    int g = t >> 12;
    int i = t & (IL - 1);
    const float* base = in + (size_t)g * (8 * IL) + i;
    uint4 v;
    v.x = (f16bits(base[1 * IL]) << 16) | f16bits(base[0 * IL]);
    v.y = (f16bits(base[3 * IL]) << 16) | f16bits(base[2 * IL]);
    v.z = (f16bits(base[5 * IL]) << 16) | f16bits(base[4 * IL]);
    v.w = (f16bits(base[7 * IL]) << 16) | f16bits(base[6 * IL]);
    reinterpret_cast<uint4*>(slab)[t] = v;
  } else {
    const int wv = threadIdx.x >> 6;
    const int o = (bid - SLAB_BLOCKS) * 4 + wv;
    const unsigned lane = threadIdx.x & 63u;
    const uint32_t r = (uint32_t)(o & 7);
    const int*   irow = idx + (size_t)o * FI;
    const float* wrow = w   + (size_t)o * FI;

    uint32_t i0 = (uint32_t)irow[lane], i1 = (uint32_t)irow[64 + lane];
    uint32_t e0 = (f16bits(wrow[lane])      << 16) | ((i0 << 4) & 0xFFFFu);
    uint32_t e1 = (f16bits(wrow[64 + lane]) << 16) | ((i1 << 4) & 0xFFFFu);
    uint32_t k0 = i0 & 7u, k1 = i1 & 7u;
    const uint64_t lt = (1ull << lane) - 1ull;

    uint32_t rank0 = 0, rank1 = 0;
    uint64_t cntp = 0;
    #pragma unroll
    for (int g = 0; g < 8; ++g) {
      uint64_t b0 = __ballot(k0 == (uint32_t)g);
      uint64_t b1 = __ballot(k1 == (uint32_t)g);
      uint32_t c0 = (uint32_t)__popcll(b0);
      if (k0 == (uint32_t)g) rank0 = (uint32_t)__popcll(b0 & lt);
      if (k1 == (uint32_t)g) rank1 = c0 + (uint32_t)__popcll(b1 & lt);
      cntp |= (uint64_t)(c0 + (uint32_t)__popcll(b1)) << (8 * g);
    }
    uint64_t ov0 = __ballot(rank0 >= 16u);
    uint64_t ov1 = __ballot(rank1 >= 16u);
    uint32_t ofr0 = (uint32_t)__popcll(ov0 & lt);
    uint32_t ofr1 = (uint32_t)__popcll(ov0) + (uint32_t)__popcll(ov1 & lt);

    auto place = [&](uint32_t k, uint32_t rank, uint32_t ofr) -> uint32_t {
      if (rank < 16u) return ((k - r) & 7u) + 8u * rank;
      uint32_t cum = 0, p = 0;
      bool done = false;
      #pragma unroll
      for (int lc = 0; lc < 8; ++lc) {
        uint32_t gl = ((uint32_t)lc + r) & 7u;
        uint32_t c  = (uint32_t)((cntp >> (8 * gl)) & 0xFFu);
        uint32_t u  = c < 16u ? c : 16u;
        uint32_t lcnt = 16u - u;
        if (!done && ofr < cum + lcnt) { p = (uint32_t)lc + 8u * (u + ofr - cum); done = true; }
        cum += lcnt;
      }
      return p;
    };
    sbuf[wv][place(k0, rank0, ofr0)] = e0;
    sbuf[wv][place(k1, rank1, ofr1)] = e1;
    __syncthreads();   // uniform branch within block: safe

    uint32_t s0 = sbuf[wv][2 * lane], s1 = sbuf[wv][2 * lane + 1];
    uint2 pe;
    pe.x = ((s0 & 0xFFFFu) << 16) | (s1 & 0xFFFFu);        // addr(f1) hi | addr(f2) lo
    pe.y = (s1 & 0xFFFF0000u) | (s0 >> 16);                // w2 hi | w1 lo
    pack2[(size_t)o * 64 + lane] = pe;
  }
}

// main kernel: asm modulo-scheduled gather pipeline.
// 4 pair-slots (8 ds_read_b128 outstanding); per region: counted lgkmcnt(6) +
// sched_barrier(0) -> consume one pair (perm+dot2) -> reissue slot with the
// next pair (cross-j regions use prefetched next pack words; pipe never drains).
__global__ __launch_bounds__(512, 4)
void lincond_kernel(const uint32_t* __restrict__ slab,
                    const uint2* __restrict__ pack2,
                    const float* __restrict__ bias,
                    float* __restrict__ out) {
  __shared__ uint32_t lds[SLAB_DW];
  const int bid   = blockIdx.x;
  const int b0    = (bid >> 3) * BTILE;
  const int obase = (bid & 7) * OTILE;
  const int tid   = threadIdx.x;

  {
    const uint32_t* src = slab + (size_t)(b0 >> 3) * SLAB_DW;
    #pragma unroll
    for (int r = 0; r < 8; ++r) {
      int e = (r * 512 + tid) * 4;
      __builtin_amdgcn_global_load_lds(
          (const __attribute__((address_space(1))) uint32_t*)(src + e),
          (__attribute__((address_space(3))) uint32_t*)(lds + e),
          16, 0, 0);
    }
  }
  __syncthreads();

  const int o = obase + tid;
  const uint32_t lb = (uint32_t)(uintptr_t)(__attribute__((address_space(3))) uint32_t*)lds;
  float acc[8] = {0.f,0.f,0.f,0.f,0.f,0.f,0.f,0.f};
  const uint4* pw4 = reinterpret_cast<const uint4*>(pack2) + (size_t)o * 32;

#define DSRD2(GA, GB, AW)                                                       \
  asm volatile("ds_read_b128 %0, %2\n\tds_read_b128 %1, %3"                     \
    : "=v"(GA), "=v"(GB)                                                        \
    : "v"(lb + ((AW) >> 16)), "v"(lb + ((AW) & 0xFFFFu)));

#define WAITL6 { asm volatile("s_waitcnt lgkmcnt(6)" ::: "memory");             \
                 __builtin_amdgcn_sched_barrier(0); }

#define DOT2P(U1, U2, WT, K0, K1) {                                             \
    acc[K0] = fdot2(as_h2(__builtin_amdgcn_perm((U2), (U1), 0x05040100u)),      \
                    as_h2(WT), acc[K0]);                                        \
    acc[K1] = fdot2(as_h2(__builtin_amdgcn_perm((U2), (U1), 0x07060302u)),      \
                    as_h2(WT), acc[K1]);}

#define CONS(GA, GB, WT) {                                                      \
    DOT2P((GA)[0], (GB)[0], WT, 0, 1)                                           \
    DOT2P((GA)[1], (GB)[1], WT, 2, 3)                                           \
    DOT2P((GA)[2], (GB)[2], WT, 4, 5)                                           \
    DOT2P((GA)[3], (GB)[3], WT, 6, 7)}

  u32x4 s0a, s0b, s1a, s1b, s2a, s2b, s3a, s3b;
  uint4 c0 = pw4[0], c1 = pw4[1], c2 = pw4[2], c3 = pw4[3];

  // prologue: pairs 0..3 of j=0 in flight (8 reads)
  DSRD2(s0a, s0b, c0.x);
  DSRD2(s1a, s1b, c0.z);
  DSRD2(s2a, s2b, c1.x);
  DSRD2(s3a, s3b, c1.z);

  #pragma unroll 1
  for (int j = 0; j < 8; ++j) {
    const int jn = ((j + 1) & 7) * 4;   // wrap: j=7 prefetches j=0 (8 extra reads, harmless)
    uint4 n0 = pw4[jn + 0], n1 = pw4[jn + 1], n2 = pw4[jn + 2], n3 = pw4[jn + 3];

    WAITL6 CONS(s0a, s0b, c0.y); DSRD2(s0a, s0b, c2.x);   // consume p0, issue p4
    WAITL6 CONS(s1a, s1b, c0.w); DSRD2(s1a, s1b, c2.z);   // p1 -> p5
    WAITL6 CONS(s2a, s2b, c1.y); DSRD2(s2a, s2b, c3.x);   // p2 -> p6
    WAITL6 CONS(s3a, s3b, c1.w); DSRD2(s3a, s3b, c3.z);   // p3 -> p7
    WAITL6 CONS(s0a, s0b, c2.y); DSRD2(s0a, s0b, n0.x);   // p4 -> next p0
    WAITL6 CONS(s1a, s1b, c2.w); DSRD2(s1a, s1b, n0.z);   // p5 -> next p1
    WAITL6 CONS(s2a, s2b, c3.y); DSRD2(s2a, s2b, n1.x);   // p6 -> next p2
    WAITL6 CONS(s3a, s3b, c3.w); DSRD2(s3a, s3b, n1.z);   // p7 -> next p3

    c0 = n0; c1 = n1; c2 = n2; c3 = n3;
  }
  asm volatile("s_waitcnt lgkmcnt(0)" ::: "memory");   // drain wrapped reads

  const float bv = bias[o];
  #pragma unroll
  for (int k = 0; k < 8; ++k)
    out[(size_t)(b0 + k) * NOUT + o] = acc[k] + bv;
}

// fallback (no workspace): naive but correct
__global__ __launch_bounds__(256)
void lincond_raw(const float* __restrict__ input, const float* __restrict__ wgt,
                 const float* __restrict__ bias, const int* __restrict__ idxs,
                 float* __restrict__ out) {
  int t = blockIdx.x * 256 + threadIdx.x;
  int b = t >> 12, o = t & (NOUT - 1);
  const float* irow = input + (size_t)b * IL;
  const int*   ix   = idxs + (size_t)o * FI;
  const float* wr   = wgt  + (size_t)o * FI;
  float acc = bias[o];
  for (int f = 0; f < FI; ++f) acc += wr[f] * irow[ix[f]];
  out[t] = acc;
}

extern "C" void kernel_launch(void* const* d_in, const int* in_sizes, int n_in,
                              void* d_out, int out_size, void* d_ws, size_t ws_size,
                              hipStream_t stream) {
  const float* input  = (const float*)d_in[0];
  const float* weight = (const float*)d_in[1];
  const float* bias   = (const float*)d_in[2];
  const int*   idxs   = (const int*)d_in[3];
  float*       out    = (float*)d_out;

  const size_t pack_bytes = (size_t)NOUT * 64 * sizeof(uint2);                 // 2 MB
  const size_t slab_bytes = (size_t)(NB / BTILE) * SLAB_DW * sizeof(uint32_t); // 8 MB
  const int grid = (NB / BTILE) * OSPLIT;                                      // 1024

  if (ws_size >= pack_bytes + slab_bytes) {
    uint2*    pack2 = (uint2*)d_ws;
    uint32_t* slab  = (uint32_t*)((char*)d_ws + pack_bytes);
    prep_kernel<<<SLAB_BLOCKS + SORT_BLOCKS, 256, 0, stream>>>(input, slab, idxs, weight, pack2);
    lincond_kernel<<<grid, 512, 0, stream>>>(slab, pack2, bias, out);
  } else {
    lincond_raw<<<(NB * NOUT) / 256, 256, 0, stream>>>(input, weight, bias, idxs, out);
  }
}

// Round 19
// 48.078 us; speedup vs baseline: 1.1997x; 1.1997x over previous
//
#include <hip/hip_runtime.h>
#include <hip/hip_fp16.h>
#include <stdint.h>

#define NB    1024
#define IL    4096
#define NOUT  4096
#define FI    128
#define BTILE 8
#define OSPLIT 4
#define OTILE (NOUT / OSPLIT)        // 1024 outputs per block
#define SLAB_DW (IL * (BTILE / 2))   // 16384 dwords = 64KB per batch-group slab
#define SLAB_BLOCKS ((NB / BTILE) * IL / 256)   // 2048
#define SORT_BLOCKS (NOUT / 4)                  // 1024 (wave per row)

typedef _Float16 h2v __attribute__((ext_vector_type(2)));
__device__ __forceinline__ h2v as_h2(uint32_t u){ union{uint32_t u; h2v h;} c; c.u=u; return c.h; }
#if __has_builtin(__builtin_amdgcn_fdot2)
__device__ __forceinline__ float fdot2(h2v a, h2v b, float c){ return __builtin_amdgcn_fdot2(a,b,c,false); }
#else
__device__ __forceinline__ float fdot2(h2v a, h2v b, float c){ return c + (float)a[0]*(float)b[0] + (float)a[1]*(float)b[1]; }
#endif

__device__ __forceinline__ uint32_t f16bits(float x) {
  return (uint32_t)__half_as_ushort(__float2half(x));   // RNE f32->f16
}

// ---------------- merged pre-pass (one launch, unchanged) ----------------
__global__ __launch_bounds__(256)
void prep_kernel(const float* __restrict__ in, uint32_t* __restrict__ slab,
                 const int* __restrict__ idx, const float* __restrict__ w,
                 uint2* __restrict__ pack2) {
  __shared__ uint32_t sbuf[4][FI];
  const int bid = blockIdx.x;
  if (bid < SLAB_BLOCKS) {
    int t = bid * 256 + threadIdx.x;
    int g = t >> 12;
    int i = t & (IL - 1);
    const float* base = in + (size_t)g * (8 * IL) + i;
    uint4 v;
    v.x = (f16bits(base[1 * IL]) << 16) | f16bits(base[0 * IL]);
    v.y = (f16bits(base[3 * IL]) << 16) | f16bits(base[2 * IL]);
    v.z = (f16bits(base[5 * IL]) << 16) | f16bits(base[4 * IL]);
    v.w = (f16bits(base[7 * IL]) << 16) | f16bits(base[6 * IL]);
    reinterpret_cast<uint4*>(slab)[t] = v;
  } else {
    const int wv = threadIdx.x >> 6;
    const int o = (bid - SLAB_BLOCKS) * 4 + wv;
    const unsigned lane = threadIdx.x & 63u;
    const uint32_t r = (uint32_t)(o & 7);
    const int*   irow = idx + (size_t)o * FI;
    const float* wrow = w   + (size_t)o * FI;

    uint32_t i0 = (uint32_t)irow[lane], i1 = (uint32_t)irow[64 + lane];
    uint32_t e0 = (f16bits(wrow[lane])      << 16) | ((i0 << 4) & 0xFFFFu);
    uint32_t e1 = (f16bits(wrow[64 + lane]) << 16) | ((i1 << 4) & 0xFFFFu);
    uint32_t k0 = i0 & 7u, k1 = i1 & 7u;
    const uint64_t lt = (1ull << lane) - 1ull;

    uint32_t rank0 = 0, rank1 = 0;
    uint64_t cntp = 0;
    #pragma unroll
    for (int g = 0; g < 8; ++g) {
      uint64_t b0 = __ballot(k0 == (uint32_t)g);
      uint64_t b1 = __ballot(k1 == (uint32_t)g);
      uint32_t c0 = (uint32_t)__popcll(b0);
      if (k0 == (uint32_t)g) rank0 = (uint32_t)__popcll(b0 & lt);
      if (k1 == (uint32_t)g) rank1 = c0 + (uint32_t)__popcll(b1 & lt);
      cntp |= (uint64_t)(c0 + (uint32_t)__popcll(b1)) << (8 * g);
    }
    uint64_t ov0 = __ballot(rank0 >= 16u);
    uint64_t ov1 = __ballot(rank1 >= 16u);
    uint32_t ofr0 = (uint32_t)__popcll(ov0 & lt);
    uint32_t ofr1 = (uint32_t)__popcll(ov0) + (uint32_t)__popcll(ov1 & lt);

    auto place = [&](uint32_t k, uint32_t rank, uint32_t ofr) -> uint32_t {
      if (rank < 16u) return ((k - r) & 7u) + 8u * rank;
      uint32_t cum = 0, p = 0;
      bool done = false;
      #pragma unroll
      for (int lc = 0; lc < 8; ++lc) {
        uint32_t gl = ((uint32_t)lc + r) & 7u;
        uint32_t c  = (uint32_t)((cntp >> (8 * gl)) & 0xFFu);
        uint32_t u  = c < 16u ? c : 16u;
        uint32_t lcnt = 16u - u;
        if (!done && ofr < cum + lcnt) { p = (uint32_t)lc + 8u * (u + ofr - cum); done = true; }
        cum += lcnt;
      }
      return p;
    };
    sbuf[wv][place(k0, rank0, ofr0)] = e0;
    sbuf[wv][place(k1, rank1, ofr1)] = e1;
    __syncthreads();   // uniform branch within block: safe

    uint32_t s0 = sbuf[wv][2 * lane], s1 = sbuf[wv][2 * lane + 1];
    uint2 pe;
    pe.x = ((s0 & 0xFFFFu) << 16) | (s1 & 0xFFFFu);        // addr(f1) hi | addr(f2) lo
    pe.y = (s1 & 0xFFFF0000u) | (s0 >> 16);                // w2 hi | w1 lo
    pack2[(size_t)o * 64 + lane] = pe;
  }
}

// main kernel: 512 threads, 2 outputs/thread, loop-carried pack prefetch,
// XCD-swizzled blockIdx so the 4 blocks sharing one slab group co-locate on
// one XCD (slab staging hits that XCD's L2 instead of L3).
__global__ __launch_bounds__(512, 4)
void lincond_kernel(const uint32_t* __restrict__ slab,
                    const uint2* __restrict__ pack2,
                    const float* __restrict__ bias,
                    float* __restrict__ out) {
  __shared__ uint32_t lds[SLAB_DW];
  const int bid   = blockIdx.x;
  const int wgid  = (bid & 7) * 64 + (bid >> 3);   // bijective: grid 512 = 8*64
  const int b0    = (wgid >> 2) * BTILE;
  const int obase = (wgid & 3) * OTILE;
  const int tid   = threadIdx.x;

  {
    const uint32_t* src = slab + (size_t)(b0 >> 3) * SLAB_DW;
    #pragma unroll
    for (int r = 0; r < 8; ++r) {
      int e = (r * 512 + tid) * 4;
      __builtin_amdgcn_global_load_lds(
          (const __attribute__((address_space(1))) uint32_t*)(src + e),
          (__attribute__((address_space(3))) uint32_t*)(lds + e),
          16, 0, 0);
    }
  }
  __syncthreads();

  const int oA = obase + tid;
  const int oB = oA + 512;
  const char* ldsb = reinterpret_cast<const char*>(lds);
  float accA[8] = {0.f,0.f,0.f,0.f,0.f,0.f,0.f,0.f};
  float accB[8] = {0.f,0.f,0.f,0.f,0.f,0.f,0.f,0.f};
  const uint4* pwA = reinterpret_cast<const uint4*>(pack2) + (size_t)oA * 32;
  const uint4* pwB = reinterpret_cast<const uint4*>(pack2) + (size_t)oB * 32;

#define RD2(AD, G1, G2) {                                                       \
    uint32_t a1_ = (AD) >> 16, a2_ = (AD) & 0xFFFFu;                            \
    G1 = *reinterpret_cast<const uint4*>(ldsb + a1_);                           \
    G2 = *reinterpret_cast<const uint4*>(ldsb + a2_); }

#define DOT2P(ACC, U1, U2, WT, K0, K1) {                                        \
    ACC[K0] = fdot2(as_h2(__builtin_amdgcn_perm((U2), (U1), 0x05040100u)),      \
                    as_h2(WT), ACC[K0]);                                        \
    ACC[K1] = fdot2(as_h2(__builtin_amdgcn_perm((U2), (U1), 0x07060302u)),      \
                    as_h2(WT), ACC[K1]);}

#define CONS(ACC, G1, G2, WT) {                                                 \
    DOT2P(ACC, (G1).x, (G2).x, WT, 0, 1)                                        \
    DOT2P(ACC, (G1).y, (G2).y, WT, 2, 3)                                        \
    DOT2P(ACC, (G1).z, (G2).z, WT, 4, 5)                                        \
    DOT2P(ACC, (G1).w, (G2).w, WT, 6, 7)}

  // prologue: j=0 pack words
  uint4 pA0 = pwA[0], pA1 = pwA[1], pA2 = pwA[2], pA3 = pwA[3];
  uint4 pB0 = pwB[0], pB1 = pwB[1], pB2 = pwB[2], pB3 = pwB[3];

  #pragma unroll 1
  for (int j = 0; j < 8; ++j) {
    const int jn = ((j + 1) & 7) * 4;
    uint4 nA0 = pwA[jn + 0], nA1 = pwA[jn + 1], nA2 = pwA[jn + 2], nA3 = pwA[jn + 3];
    uint4 nB0 = pwB[jn + 0], nB1 = pwB[jn + 1], nB2 = pwB[jn + 2], nB3 = pwB[jn + 3];

    uint4 aA1, aA2, bA1, bA2;
    uint4 aB1, aB2, bB1, bB2;

    RD2(pA0.x, aA1, aA2);  RD2(pB0.x, aB1, aB2);
    RD2(pA0.z, bA1, bA2);  CONS(accA, aA1, aA2, pA0.y);
    RD2(pB0.z, bB1, bB2);  CONS(accB, aB1, aB2, pB0.y);
    RD2(pA1.x, aA1, aA2);  CONS(accA, bA1, bA2, pA0.w);
    RD2(pB1.x, aB1, aB2);  CONS(accB, bB1, bB2, pB0.w);
    RD2(pA1.z, bA1, bA2);  CONS(accA, aA1, aA2, pA1.y);
    RD2(pB1.z, bB1, bB2);  CONS(accB, aB1, aB2, pB1.y);
    RD2(pA2.x, aA1, aA2);  CONS(accA, bA1, bA2, pA1.w);
    RD2(pB2.x, aB1, aB2);  CONS(accB, bB1, bB2, pB1.w);
    RD2(pA2.z, bA1, bA2);  CONS(accA, aA1, aA2, pA2.y);
    RD2(pB2.z, bB1, bB2);  CONS(accB, aB1, aB2, pB2.y);
    RD2(pA3.x, aA1, aA2);  CONS(accA, bA1, bA2, pA2.w);
    RD2(pB3.x, aB1, aB2);  CONS(accB, bB1, bB2, pB2.w);
    RD2(pA3.z, bA1, bA2);  CONS(accA, aA1, aA2, pA3.y);
    RD2(pB3.z, bB1, bB2);  CONS(accB, aB1, aB2, pB3.y);
                           CONS(accA, bA1, bA2, pA3.w);
                           CONS(accB, bB1, bB2, pB3.w);

    pA0 = nA0; pA1 = nA1; pA2 = nA2; pA3 = nA3;
    pB0 = nB0; pB1 = nB1; pB2 = nB2; pB3 = nB3;
  }

  const float bvA = bias[oA];
  const float bvB = bias[oB];
  #pragma unroll
  for (int k = 0; k < 8; ++k) {
    out[(size_t)(b0 + k) * NOUT + oA] = accA[k] + bvA;
    out[(size_t)(b0 + k) * NOUT + oB] = accB[k] + bvB;
  }
}

// fallback (no workspace): naive but correct
__global__ __launch_bounds__(256)
void lincond_raw(const float* __restrict__ input, const float* __restrict__ wgt,
                 const float* __restrict__ bias, const int* __restrict__ idxs,
                 float* __restrict__ out) {
  int t = blockIdx.x * 256 + threadIdx.x;
  int b = t >> 12, o = t & (NOUT - 1);
  const float* irow = input + (size_t)b * IL;
  const int*   ix   = idxs + (size_t)o * FI;
  const float* wr   = wgt  + (size_t)o * FI;
  float acc = bias[o];
  for (int f = 0; f < FI; ++f) acc += wr[f] * irow[ix[f]];
  out[t] = acc;
}

extern "C" void kernel_launch(void* const* d_in, const int* in_sizes, int n_in,
                              void* d_out, int out_size, void* d_ws, size_t ws_size,
                              hipStream_t stream) {
  const float* input  = (const float*)d_in[0];
  const float* weight = (const float*)d_in[1];
  const float* bias   = (const float*)d_in[2];
  const int*   idxs   = (const int*)d_in[3];
  float*       out    = (float*)d_out;

  const size_t pack_bytes = (size_t)NOUT * 64 * sizeof(uint2);                 // 2 MB
  const size_t slab_bytes = (size_t)(NB / BTILE) * SLAB_DW * sizeof(uint32_t); // 8 MB
  const int grid = (NB / BTILE) * OSPLIT;                                      // 512

  if (ws_size >= pack_bytes + slab_bytes) {
    uint2*    pack2 = (uint2*)d_ws;
    uint32_t* slab  = (uint32_t*)((char*)d_ws + pack_bytes);
    prep_kernel<<<SLAB_BLOCKS + SORT_BLOCKS, 256, 0, stream>>>(input, slab, idxs, weight, pack2);
    lincond_kernel<<<grid, 512, 0, stream>>>(slab, pack2, bias, out);
  } else {
    lincond_raw<<<(NB * NOUT) / 256, 256, 0, stream>>>(input, weight, bias, idxs, out);
  }
}

// Round 22
// 47.824 us; speedup vs baseline: 1.2061x; 1.0053x over previous
//
#include <hip/hip_runtime.h>
#include <hip/hip_fp16.h>
#include <stdint.h>

#define NB    1024
#define IL    4096
#define NOUT  4096
#define FI    128
#define BTILE 8
#define OSPLIT 4
#define OTILE (NOUT / OSPLIT)        // 1024 outputs per block
#define SLAB_DW (IL * (BTILE / 2))   // 16384 dwords = 64KB per batch-group slab
#define SLAB_BLOCKS ((NB / BTILE) * IL / 256)   // 2048
#define SORT_BLOCKS (NOUT / 4)                  // 1024 (wave per row)

typedef _Float16 h2v __attribute__((ext_vector_type(2)));
__device__ __forceinline__ h2v as_h2(uint32_t u){ union{uint32_t u; h2v h;} c; c.u=u; return c.h; }
#if __has_builtin(__builtin_amdgcn_fdot2)
__device__ __forceinline__ float fdot2(h2v a, h2v b, float c){ return __builtin_amdgcn_fdot2(a,b,c,false); }
#else
__device__ __forceinline__ float fdot2(h2v a, h2v b, float c){ return c + (float)a[0]*(float)b[0] + (float)a[1]*(float)b[1]; }
#endif

__device__ __forceinline__ uint32_t f16bits(float x) {
  return (uint32_t)__half_as_ushort(__float2half(x));   // RNE f32->f16
}

// ---------------- merged pre-pass (one launch) ----------------
// bid <  SLAB_BLOCKS : f16 slab  row i = uint4 = 8 batches f16
// bid >= SLAB_BLOCKS : comb-sorted PAIRED pack (wave per row, ballot ranks)
__global__ __launch_bounds__(256)
void prep_kernel(const float* __restrict__ in, uint32_t* __restrict__ slab,
                 const int* __restrict__ idx, const float* __restrict__ w,
                 uint2* __restrict__ pack2) {
  __shared__ uint32_t sbuf[4][FI];
  const int bid = blockIdx.x;
  if (bid < SLAB_BLOCKS) {
    int t = bid * 256 + threadIdx.x;
    int g = t >> 12;
    int i = t & (IL - 1);
    const float* base = in + (size_t)g * (8 * IL) + i;
    uint4 v;
    v.x = (f16bits(base[1 * IL]) << 16) | f16bits(base[0 * IL]);
    v.y = (f16bits(base[3 * IL]) << 16) | f16bits(base[2 * IL]);
    v.z = (f16bits(base[5 * IL]) << 16) | f16bits(base[4 * IL]);
    v.w = (f16bits(base[7 * IL]) << 16) | f16bits(base[6 * IL]);
    reinterpret_cast<uint4*>(slab)[t] = v;
  } else {
    const int wv = threadIdx.x >> 6;
    const int o = (bid - SLAB_BLOCKS) * 4 + wv;
    const unsigned lane = threadIdx.x & 63u;
    const uint32_t r = (uint32_t)(o & 7);
    const int*   irow = idx + (size_t)o * FI;
    const float* wrow = w   + (size_t)o * FI;

    uint32_t i0 = (uint32_t)irow[lane], i1 = (uint32_t)irow[64 + lane];
    uint32_t e0 = (f16bits(wrow[lane])      << 16) | ((i0 << 4) & 0xFFFFu);
    uint32_t e1 = (f16bits(wrow[64 + lane]) << 16) | ((i1 << 4) & 0xFFFFu);
    uint32_t k0 = i0 & 7u, k1 = i1 & 7u;
    const uint64_t lt = (1ull << lane) - 1ull;

    uint32_t rank0 = 0, rank1 = 0;
    uint64_t cntp = 0;
    #pragma unroll
    for (int g = 0; g < 8; ++g) {
      uint64_t b0 = __ballot(k0 == (uint32_t)g);
      uint64_t b1 = __ballot(k1 == (uint32_t)g);
      uint32_t c0 = (uint32_t)__popcll(b0);
      if (k0 == (uint32_t)g) rank0 = (uint32_t)__popcll(b0 & lt);
      if (k1 == (uint32_t)g) rank1 = c0 + (uint32_t)__popcll(b1 & lt);
      cntp |= (uint64_t)(c0 + (uint32_t)__popcll(b1)) << (8 * g);
    }
    uint64_t ov0 = __ballot(rank0 >= 16u);
    uint64_t ov1 = __ballot(rank1 >= 16u);
    uint32_t ofr0 = (uint32_t)__popcll(ov0 & lt);
    uint32_t ofr1 = (uint32_t)__popcll(ov0) + (uint32_t)__popcll(ov1 & lt);

    auto place = [&](uint32_t k, uint32_t rank, uint32_t ofr) -> uint32_t {
      if (rank < 16u) return ((k - r) & 7u) + 8u * rank;
      uint32_t cum = 0, p = 0;
      bool done = false;
      #pragma unroll
      for (int lc = 0; lc < 8; ++lc) {
        uint32_t gl = ((uint32_t)lc + r) & 7u;
        uint32_t c  = (uint32_t)((cntp >> (8 * gl)) & 0xFFu);
        uint32_t u  = c < 16u ? c : 16u;
        uint32_t lcnt = 16u - u;
        if (!done && ofr < cum + lcnt) { p = (uint32_t)lc + 8u * (u + ofr - cum); done = true; }
        cum += lcnt;
      }
      return p;
    };
    sbuf[wv][place(k0, rank0, ofr0)] = e0;
    sbuf[wv][place(k1, rank1, ofr1)] = e1;
    __syncthreads();   // uniform branch within block: safe

    uint32_t s0 = sbuf[wv][2 * lane], s1 = sbuf[wv][2 * lane + 1];
    uint2 pe;
    pe.x = ((s0 & 0xFFFFu) << 16) | (s1 & 0xFFFFu);        // addr(f1) hi | addr(f2) lo
    pe.y = (s1 & 0xFFFF0000u) | (s0 >> 16);                // w2 hi | w1 lo
    pack2[(size_t)o * 64 + lane] = pe;
  }
}

// main kernel: 512 threads, 2 outputs/thread, loop-carried pack prefetch,
// XCD-swizzled blockIdx so the 4 blocks sharing one slab group co-locate on
// one XCD (slab staging hits that XCD's L2 instead of L3).
__global__ __launch_bounds__(512, 4)
void lincond_kernel(const uint32_t* __restrict__ slab,
                    const uint2* __restrict__ pack2,
                    const float* __restrict__ bias,
                    float* __restrict__ out) {
  __shared__ uint32_t lds[SLAB_DW];
  const int bid   = blockIdx.x;
  const int wgid  = (bid & 7) * 64 + (bid >> 3);   // bijective: grid 512 = 8*64
  const int b0    = (wgid >> 2) * BTILE;
  const int obase = (wgid & 3) * OTILE;
  const int tid   = threadIdx.x;

  {
    const uint32_t* src = slab + (size_t)(b0 >> 3) * SLAB_DW;
    #pragma unroll
    for (int r = 0; r < 8; ++r) {
      int e = (r * 512 + tid) * 4;
      __builtin_amdgcn_global_load_lds(
          (const __attribute__((address_space(1))) uint32_t*)(src + e),
          (__attribute__((address_space(3))) uint32_t*)(lds + e),
          16, 0, 0);
    }
  }
  __syncthreads();

  const int oA = obase + tid;
  const int oB = oA + 512;
  const char* ldsb = reinterpret_cast<const char*>(lds);
  float accA[8] = {0.f,0.f,0.f,0.f,0.f,0.f,0.f,0.f};
  float accB[8] = {0.f,0.f,0.f,0.f,0.f,0.f,0.f,0.f};
  const uint4* pwA = reinterpret_cast<const uint4*>(pack2) + (size_t)oA * 32;
  const uint4* pwB = reinterpret_cast<const uint4*>(pack2) + (size_t)oB * 32;

#define RD2(AD, G1, G2) {                                                       \
    uint32_t a1_ = (AD) >> 16, a2_ = (AD) & 0xFFFFu;                            \
    G1 = *reinterpret_cast<const uint4*>(ldsb + a1_);                           \
    G2 = *reinterpret_cast<const uint4*>(ldsb + a2_); }

#define DOT2P(ACC, U1, U2, WT, K0, K1) {                                        \
    ACC[K0] = fdot2(as_h2(__builtin_amdgcn_perm((U2), (U1), 0x05040100u)),      \
                    as_h2(WT), ACC[K0]);                                        \
    ACC[K1] = fdot2(as_h2(__builtin_amdgcn_perm((U2), (U1), 0x07060302u)),      \
                    as_h2(WT), ACC[K1]);}

#define CONS(ACC, G1, G2, WT) {                                                 \
    DOT2P(ACC, (G1).x, (G2).x, WT, 0, 1)                                        \
    DOT2P(ACC, (G1).y, (G2).y, WT, 2, 3)                                        \
    DOT2P(ACC, (G1).z, (G2).z, WT, 4, 5)                                        \
    DOT2P(ACC, (G1).w, (G2).w, WT, 6, 7)}

  // prologue: j=0 pack words
  uint4 pA0 = pwA[0], pA1 = pwA[1], pA2 = pwA[2], pA3 = pwA[3];
  uint4 pB0 = pwB[0], pB1 = pwB[1], pB2 = pwB[2], pB3 = pwB[3];

  #pragma unroll 1
  for (int j = 0; j < 8; ++j) {
    const int jn = ((j + 1) & 7) * 4;
    uint4 nA0 = pwA[jn + 0], nA1 = pwA[jn + 1], nA2 = pwA[jn + 2], nA3 = pwA[jn + 3];
    uint4 nB0 = pwB[jn + 0], nB1 = pwB[jn + 1], nB2 = pwB[jn + 2], nB3 = pwB[jn + 3];

    uint4 aA1, aA2, bA1, bA2;
    uint4 aB1, aB2, bB1, bB2;

    RD2(pA0.x, aA1, aA2);  RD2(pB0.x, aB1, aB2);
    RD2(pA0.z, bA1, bA2);  CONS(accA, aA1, aA2, pA0.y);
    RD2(pB0.z, bB1, bB2);  CONS(accB, aB1, aB2, pB0.y);
    RD2(pA1.x, aA1, aA2);  CONS(accA, bA1, bA2, pA0.w);
    RD2(pB1.x, aB1, aB2);  CONS(accB, bB1, bB2, pB0.w);
    RD2(pA1.z, bA1, bA2);  CONS(accA, aA1, aA2, pA1.y);
    RD2(pB1.z, bB1, bB2);  CONS(accB, aB1, aB2, pB1.y);
    RD2(pA2.x, aA1, aA2);  CONS(accA, bA1, bA2, pA1.w);
    RD2(pB2.x, aB1, aB2);  CONS(accB, bB1, bB2, pB1.w);
    RD2(pA2.z, bA1, bA2);  CONS(accA, aA1, aA2, pA2.y);
    RD2(pB2.z, bB1, bB2);  CONS(accB, aB1, aB2, pB2.y);
    RD2(pA3.x, aA1, aA2);  CONS(accA, bA1, bA2, pA2.w);
    RD2(pB3.x, aB1, aB2);  CONS(accB, bB1, bB2, pB2.w);
    RD2(pA3.z, bA1, bA2);  CONS(accA, aA1, aA2, pA3.y);
    RD2(pB3.z, bB1, bB2);  CONS(accB, aB1, aB2, pB3.y);
                           CONS(accA, bA1, bA2, pA3.w);
                           CONS(accB, bB1, bB2, pB3.w);

    pA0 = nA0; pA1 = nA1; pA2 = nA2; pA3 = nA3;
    pB0 = nB0; pB1 = nB1; pB2 = nB2; pB3 = nB3;
  }

  const float bvA = bias[oA];
  const float bvB = bias[oB];
  #pragma unroll
  for (int k = 0; k < 8; ++k) {
    out[(size_t)(b0 + k) * NOUT + oA] = accA[k] + bvA;
    out[(size_t)(b0 + k) * NOUT + oB] = accB[k] + bvB;
  }
}

// fallback (no workspace): naive but correct
__global__ __launch_bounds__(256)
void lincond_raw(const float* __restrict__ input, const float* __restrict__ wgt,
                 const float* __restrict__ bias, const int* __restrict__ idxs,
                 float* __restrict__ out) {
  int t = blockIdx.x * 256 + threadIdx.x;
  int b = t >> 12, o = t & (NOUT - 1);
  const float* irow = input + (size_t)b * IL;
  const int*   ix   = idxs + (size_t)o * FI;
  const float* wr   = wgt  + (size_t)o * FI;
  float acc = bias[o];
  for (int f = 0; f < FI; ++f) acc += wr[f] * irow[ix[f]];
  out[t] = acc;
}

extern "C" void kernel_launch(void* const* d_in, const int* in_sizes, int n_in,
                              void* d_out, int out_size, void* d_ws, size_t ws_size,
                              hipStream_t stream) {
  const float* input  = (const float*)d_in[0];
  const float* weight = (const float*)d_in[1];
  const float* bias   = (const float*)d_in[2];
  const int*   idxs   = (const int*)d_in[3];
  float*       out    = (float*)d_out;

  const size_t pack_bytes = (size_t)NOUT * 64 * sizeof(uint2);                 // 2 MB
  const size_t slab_bytes = (size_t)(NB / BTILE) * SLAB_DW * sizeof(uint32_t); // 8 MB
  const int grid = (NB / BTILE) * OSPLIT;                                      // 512

  if (ws_size >= pack_bytes + slab_bytes) {
    uint2*    pack2 = (uint2*)d_ws;
    uint32_t* slab  = (uint32_t*)((char*)d_ws + pack_bytes);
    prep_kernel<<<SLAB_BLOCKS + SORT_BLOCKS, 256, 0, stream>>>(input, slab, idxs, weight, pack2);
    lincond_kernel<<<grid, 512, 0, stream>>>(slab, pack2, bias, out);
  } else {
    lincond_raw<<<(NB * NOUT) / 256, 256, 0, stream>>>(input, weight, bias, idxs, out);
  }
}